// Round 10
// baseline (454.029 us; speedup 1.0000x reference)
//
#include <hip/hip_runtime.h>

#define BATCH 1024
#define TT    200
#define EE    100
#define HH    200
#define GG    600   // 3*HH
#define NI    50000
#define NKT   7     // scan k-tiles: 224 = 7*32 (K=200 padded)
#define KPAD  224
#define HSTR  264   // LDS h row stride in f16 (cols 200-255 = pad/dump, stay 0)
#define NTILE3 3125 // 50000/16 output n-tiles
#define NTW   50    // ewi n'-tiles: N'=800 = 50*16
#define KTW   4     // ewi k-tiles: K=100 padded to 128

typedef _Float16 half8 __attribute__((ext_vector_type(8)));
typedef _Float16 half4v __attribute__((ext_vector_type(4)));
typedef float   float4v __attribute__((ext_vector_type(4)));

static __device__ __forceinline__ float4v mfma16(half8 a, half8 b, float4v c) {
    return __builtin_amdgcn_mfma_f32_16x16x32_f16(a, b, c, 0, 0, 0);
}

#if __has_builtin(__builtin_amdgcn_rcpf)
static __device__ __forceinline__ float fastrcp(float x) { return __builtin_amdgcn_rcpf(x); }
#else
static __device__ __forceinline__ float fastrcp(float x) { return 1.f / x; }
#endif

static __device__ __forceinline__ float sigm(float x) {
    return fastrcp(1.f + __expf(-x));
}
static __device__ __forceinline__ float tanh_fast(float x) {
    float e = __expf(2.f * fabsf(x));
    float t = 1.f - 2.f * fastrcp(e + 1.f);
    return __builtin_copysignf(t, x);
}

// ---------------- K0: fused repack of Wi (+biP) and Wh into f16 MFMA fragments ----------------
// bx < 200: Wif[(nt*4+kt)*64+lane], n'=4c+g packing; bx >= 200: Whf (48 gate-tiles x 7 kt).
// NOTE: Whf's lane->element map (lane holds Wh[k=kt*32+lhi*8+j][g*200+tc*16+l15]) is
// simultaneously the B-frag layout (B[k][n]) AND the A-frag layout for Wh^T (A[m][k]) —
// the transposed scan consumes it as the A operand unchanged.
__global__ __launch_bounds__(64) void repack_all(const float* __restrict__ Wi,
                                                 const float* __restrict__ bi,
                                                 const float* __restrict__ Wh,
                                                 half8* __restrict__ Wif,
                                                 float* __restrict__ biP,
                                                 half8* __restrict__ Whf) {
    const int bx   = blockIdx.x;
    const int lane = threadIdx.x;
    const int l15  = lane & 15;
    const int lhi  = lane >> 4;
    if (bx < NTW * KTW) {
        const int kt = bx & 3;
        const int nt = bx >> 2;
        const int np = nt * 16 + l15;     // n' in [0,800)
        const int c  = np >> 2;
        const int g  = np & 3;
        half8 v;
        #pragma unroll
        for (int j = 0; j < 8; ++j) {
            int k = kt * 32 + lhi * 8 + j;
            float w = (k < EE && g < 3) ? Wi[(size_t)k * GG + g * HH + c] : 0.f;
            v[j] = (_Float16)w;
        }
        Wif[(size_t)bx * 64 + lane] = v;
        if (kt == 0 && lhi == 0)
            biP[np] = (g < 3) ? bi[g * HH + c] : 0.f;
    } else {
        const int b2   = bx - NTW * KTW;   // 0..335
        const int kt   = b2 % NKT;
        const int tile = b2 / NKT;
        const int g    = tile / 16;
        const int tc   = tile % 16;
        const int col  = tc * 16 + l15;
        half8 v;
        #pragma unroll
        for (int j = 0; j < 8; ++j) {
            int k = kt * 32 + lhi * 8 + j;
            float w = (k < HH && col < HH) ? Wh[(size_t)k * GG + g * HH + col] : 0.f;
            v[j] = (_Float16)w;
        }
        Whf[(size_t)b2 * 64 + lane] = v;
    }
}

// ---------------- K1: EWi16 = embed @ Wi (+bi, row0=bi) via f16 MFMA, 2 m-tiles/wave ----------------
__global__ __launch_bounds__(256) void ewi_mfma(const float* __restrict__ embed,
                                                const half8* __restrict__ Wif,
                                                const float* __restrict__ biP,
                                                _Float16* __restrict__ EWi16) {
    const int tid  = threadIdx.x;
    const int w    = tid >> 6;
    const int lane = tid & 63;
    const int l15  = lane & 15;
    const int lhi  = lane >> 4;

    const int mtb   = (blockIdx.x * 4 + w) * 2;
    const bool liveA = (mtb < NTILE3);
    const bool liveB = (mtb + 1 < NTILE3);
    if (!liveA) return;                      // wave-uniform, kernel has no barriers
    const int i0a = mtb * 16;
    const int i0b = liveB ? (mtb + 1) * 16 : i0a;

    half8 aA[KTW], aB[KTW];
    #pragma unroll
    for (int kt = 0; kt < KTW; ++kt) {
        const int k0 = kt * 32 + lhi * 8;
        const float* erA = embed + (size_t)(i0a + l15) * EE + k0;
        const float* erB = embed + (size_t)(i0b + l15) * EE + k0;
        #pragma unroll
        for (int j = 0; j < 8; ++j) {
            aA[kt][j] = (k0 + j < EE) ? (_Float16)erA[j] : (_Float16)0.f;
            aB[kt][j] = (k0 + j < EE) ? (_Float16)erB[j] : (_Float16)0.f;
        }
    }

    for (int nt = 0; nt < NTW; ++nt) {
        const half8* bfp = Wif + (size_t)nt * KTW * 64 + lane;
        float4v accA = (float4v){0.f, 0.f, 0.f, 0.f};
        float4v accB = (float4v){0.f, 0.f, 0.f, 0.f};
        #pragma unroll
        for (int kt = 0; kt < KTW; ++kt) {
            const half8 bf = bfp[kt * 64];
            accA = mfma16(aA[kt], bf, accA);
            accB = mfma16(aB[kt], bf, accB);
        }
        const float biv = biP[nt * 16 + l15];
        #pragma unroll
        for (int r = 0; r < 4; ++r) {
            const int rowA = i0a + lhi * 4 + r;
            float valA = accA[r] + biv;
            if (rowA == 0) valA = biv;       // q==0 padding row: bias only
            EWi16[(size_t)rowA * 800 + nt * 16 + l15] = (_Float16)valA;
        }
        if (liveB) {
            #pragma unroll
            for (int r = 0; r < 4; ++r) {
                const int rowB = i0b + lhi * 4 + r;
                EWi16[(size_t)rowB * 800 + nt * 16 + l15] = (_Float16)(accB[r] + biv);
            }
        }
    }
}

// ---------------- K2: TRANSPOSED weight-stationary MFMA GRU scan ----------------
// gh^T = Wh^T @ h^T: A = Whf (stationary, 42 frags), B = h^T from LDS (identical
// conflict-free b128 pattern as before). C[whcol][batch]: col=lane&15=batch ->
// 16 REAL batch rows per block (64 blocks), 4x MFMA efficiency vs round 9.
// Lane (l15,lhi) holds (r,z,n) accs for whcols tc*16+lhi*4+0..3 at batch l15:
// combine is fully lane-local -> accbuf redistribute DELETED.
__global__ __launch_bounds__(512, 2) void scan_mfma(const int* __restrict__ q,
                                                    const _Float16* __restrict__ EWi16,
                                                    const half8* __restrict__ Whf,
                                                    const float* __restrict__ bhn,
                                                    _Float16* __restrict__ h16g) {
    __shared__ __align__(16) _Float16 hbuf[2][16 * HSTR];
    __shared__ int qs[TT][16];               // t-major: broadcast-friendly read

    const int tid  = threadIdx.x;
    const int w    = tid >> 6;
    const int lane = tid & 63;
    const int l15  = lane & 15;              // = batch row in C
    const int lhi  = lane >> 4;
    const int b0   = blockIdx.x * 16;

    for (int idx = tid; idx < 2 * 16 * HSTR; idx += 512)
        ((_Float16*)hbuf)[idx] = (_Float16)0.f;
    for (int idx = tid; idx < 16 * TT; idx += 512) {
        int b = idx & 15, t = idx >> 4;
        qs[t][b] = q[(size_t)(b0 + b) * TT + t];
    }

    // --- register-resident Wh^T A-fragments: [gate][c2][kt] (same Whf buffer) ---
    half8 wa[3][2][7];
    #pragma unroll
    for (int g = 0; g < 3; ++g) {
        #pragma unroll
        for (int c2 = 0; c2 < 2; ++c2) {
            const int tc = w + c2 * 8;
            #pragma unroll
            for (int kt = 0; kt < NKT; ++kt)
                wa[g][c2][kt] = Whf[((size_t)(g * 16 + tc) * NKT + kt) * 64 + lane];
        }
    }

    const int cb0  = w * 16 + lhi * 4;        // whcol base, tc=w   (0..124, always valid)
    const int cb1  = (w + 8) * 16 + lhi * 4;  // whcol base, tc=w+8 (128..252)
    const bool pad1 = (cb1 >= HH);            // all-4-pad iff cb1 >= 200 (step 4)
    const int gb1  = pad1 ? 0 : cb1;          // clamped gi read base (finite data)

    float bh0[4], bh1[4];
    #pragma unroll
    for (int r = 0; r < 4; ++r) {
        bh0[r] = bhn[cb0 + r];                                    // cb0+3 <= 127
        int c1 = cb1 + r; bh1[r] = bhn[c1 < HH ? c1 : 0];
    }

    float hr0[4] = {0.f, 0.f, 0.f, 0.f};      // h_old for this lane's cols
    float hr1[4] = {0.f, 0.f, 0.f, 0.f};

    __syncthreads();

    half8 g0a, g0b, g1a, g1b;                 // gi: [cols cb+0,cb+1 | cb+2,cb+3] x 2 halves
    #define LOADGI(tt) do {                                                  \
        const int tl = (tt) < TT ? (tt) : (TT - 1);                          \
        const int qv = qs[tl][l15];                                          \
        const _Float16* ew = EWi16 + (size_t)qv * 800;                       \
        g0a = *(const half8*)(ew + cb0 * 4);                                 \
        g0b = *(const half8*)(ew + cb0 * 4 + 8);                             \
        g1a = *(const half8*)(ew + gb1 * 4);                                 \
        g1b = *(const half8*)(ew + gb1 * 4 + 8);                             \
    } while (0)

    LOADGI(0);

    #define COMBINE_HALF(ga, gb, aR, aZ, aN, bh, hr, cbase, isPad) do {      \
        half4v hv4;                                                          \
        _Pragma("unroll")                                                    \
        for (int r = 0; r < 4; ++r) {                                        \
            float gr, gz, gn;                                                \
            if      (r == 0) { gr = (float)ga[0]; gz = (float)ga[1]; gn = (float)ga[2]; } \
            else if (r == 1) { gr = (float)ga[4]; gz = (float)ga[5]; gn = (float)ga[6]; } \
            else if (r == 2) { gr = (float)gb[0]; gz = (float)gb[1]; gn = (float)gb[2]; } \
            else             { gr = (float)gb[4]; gz = (float)gb[5]; gn = (float)gb[6]; } \
            float rr = sigm(gr + aR[r]);                                     \
            float zz = sigm(gz + aZ[r]);                                     \
            float nn = tanh_fast(gn + rr * (aN[r] + bh[r]));                 \
            float hv = (1.f - zz) * nn + zz * hr[r];                         \
            if (isPad) hv = 0.f;          /* keep pad cols clean (no NaN) */ \
            hr[r] = hv;                                                      \
            hv4[r] = (_Float16)hv;                                           \
        }                                                                    \
        *(half4v*)(hn + l15 * HSTR + (cbase)) = hv4;                         \
    } while (0)

    #define STEP(CUR, NXT, TLOAD) do {                                       \
        const _Float16* hb = &hbuf[CUR][0];                                  \
        _Float16*       hn = &hbuf[NXT][0];                                  \
        half8 bf[NKT];                                                       \
        _Pragma("unroll")                                                    \
        for (int kt = 0; kt < NKT; ++kt)                                     \
            bf[kt] = *(const half8*)(hb + l15 * HSTR + kt * 32 + lhi * 8);   \
        {                                                                    \
            float4v aR = (float4v){0.f,0.f,0.f,0.f};                         \
            float4v aZ = (float4v){0.f,0.f,0.f,0.f};                         \
            float4v aN = (float4v){0.f,0.f,0.f,0.f};                         \
            _Pragma("unroll")                                                \
            for (int kt = 0; kt < NKT; ++kt) {                               \
                aR = mfma16(wa[0][0][kt], bf[kt], aR);                       \
                aZ = mfma16(wa[1][0][kt], bf[kt], aZ);                       \
                aN = mfma16(wa[2][0][kt], bf[kt], aN);                       \
            }                                                                \
            COMBINE_HALF(g0a, g0b, aR, aZ, aN, bh0, hr0, cb0, false);        \
        }                                                                    \
        {                                                                    \
            float4v aR = (float4v){0.f,0.f,0.f,0.f};                         \
            float4v aZ = (float4v){0.f,0.f,0.f,0.f};                         \
            float4v aN = (float4v){0.f,0.f,0.f,0.f};                         \
            _Pragma("unroll")                                                \
            for (int kt = 0; kt < NKT; ++kt) {                               \
                aR = mfma16(wa[0][1][kt], bf[kt], aR);                       \
                aZ = mfma16(wa[1][1][kt], bf[kt], aZ);                       \
                aN = mfma16(wa[2][1][kt], bf[kt], aN);                       \
            }                                                                \
            COMBINE_HALF(g1a, g1b, aR, aZ, aN, bh1, hr1, cb1, pad1);         \
        }                                                                    \
        LOADGI(TLOAD);   /* 1-step prefetch: covered by next MFMA phase */   \
        __syncthreads();                                                     \
    } while (0)

    for (int t = 0; t < TT; t += 2) {
        STEP(0, 1, t + 1);
        STEP(1, 0, t + 2);
    }
    #undef STEP
    #undef COMBINE_HALF
    #undef LOADGI

    // ---- export h_last: 16 rows x KPAD (cols 200-223 are forced zeros) ----
    for (int idx = tid; idx < 16 * KPAD; idx += 512) {
        int b = idx / KPAD, k = idx % KPAD;
        h16g[(size_t)(b0 + b) * KPAD + k] = hbuf[0][b * HSTR + k];
    }
}

// ---------------- K3: out = h_last @ Wo + bo via f16 MFMA, 2 n-tiles/wave ----------------
__global__ __launch_bounds__(256) void out_mfma(const _Float16* __restrict__ h16g,
                                                const float* __restrict__ Wo,
                                                const float* __restrict__ bo,
                                                float* __restrict__ out) {
    const int tid  = threadIdx.x;
    const int w    = tid >> 6;
    const int lane = tid & 63;
    const int l15  = lane & 15;
    const int lhi  = lane >> 4;

    const int ntb   = (blockIdx.x * 4 + w) * 2;
    const bool liveA = (ntb < NTILE3);
    const bool liveB = (ntb + 1 < NTILE3);
    const int ntA = liveA ? ntb : (NTILE3 - 1);
    const int ntB = liveB ? (ntb + 1) : (NTILE3 - 1);
    const int colA = ntA * 16 + l15;
    const int colB = ntB * 16 + l15;

    half8 wbA[7], wbB[7];
    #pragma unroll
    for (int kt = 0; kt < NKT; ++kt) {
        #pragma unroll
        for (int j = 0; j < 8; ++j) {
            int k = kt * 32 + lhi * 8 + j;
            wbA[kt][j] = (k < HH) ? (_Float16)Wo[(size_t)k * NI + colA] : (_Float16)0.f;
            wbB[kt][j] = (k < HH) ? (_Float16)Wo[(size_t)k * NI + colB] : (_Float16)0.f;
        }
    }
    const float bovA = bo[colA];
    const float bovB = bo[colB];

    for (int mt = 0; mt < BATCH / 16; ++mt) {
        const _Float16* hrow = h16g + (size_t)(mt * 16 + l15) * KPAD + lhi * 8;
        float4v accA = (float4v){0.f, 0.f, 0.f, 0.f};
        float4v accB = (float4v){0.f, 0.f, 0.f, 0.f};
        #pragma unroll
        for (int kt = 0; kt < NKT; ++kt) {
            const half8 af = *(const half8*)(hrow + kt * 32);
            accA = mfma16(af, wbA[kt], accA);
            accB = mfma16(af, wbB[kt], accB);
        }
        if (liveA) {
            #pragma unroll
            for (int r = 0; r < 4; ++r) {
                int row = mt * 16 + lhi * 4 + r;
                out[(size_t)row * NI + colA] = accA[r] + bovA;
            }
        }
        if (liveB) {
            #pragma unroll
            for (int r = 0; r < 4; ++r) {
                int row = mt * 16 + lhi * 4 + r;
                out[(size_t)row * NI + colB] = accB[r] + bovB;
            }
        }
    }
}

extern "C" void kernel_launch(void* const* d_in, const int* in_sizes, int n_in,
                              void* d_out, int out_size, void* d_ws, size_t ws_size,
                              hipStream_t stream) {
    const int*   q     = (const int*)d_in[0];
    const float* embed = (const float*)d_in[1];
    const float* Wi    = (const float*)d_in[2];
    const float* bi    = (const float*)d_in[3];
    const float* Wh    = (const float*)d_in[4];
    const float* bhn   = (const float*)d_in[5];
    const float* Wo    = (const float*)d_in[6];
    const float* bo    = (const float*)d_in[7];
    float* out = (float*)d_out;

    // Scratch layout in d_out (204.8 MB), consumed before K3 overwrites it:
    //   EWi16 [50000 x 200 x 4] f16 = 80,000,000 B at +0
    //   Whf   [48*7 frags]      f16 =    344,064 B at +120,000,000
    //   Wif   [50*4 frags]      f16 =    204,800 B at +121,000,000
    //   biP   [800]             f32 =      3,200 B at +122,000,000
    //   h16g  [1024 x 224] f16 = 458,752 B in d_ws
    _Float16* EWi16 = (_Float16*)d_out;
    half8*    Whf   = (half8*)((char*)d_out + 120000000);
    half8*    Wif   = (half8*)((char*)d_out + 121000000);
    float*    biP   = (float*)((char*)d_out + 122000000);
    _Float16* h16g  = (_Float16*)d_ws;

    repack_all<<<NTW * KTW + 48 * NKT, 64, 0, stream>>>(Wi, bi, Wh, Wif, biP, Whf);
    ewi_mfma<<<(NTILE3 / 2 + 3) / 4, 256, 0, stream>>>(embed, Wif, biP, EWi16);
    scan_mfma<<<BATCH / 16, 512, 0, stream>>>(q, EWi16, Whf, bhn, h16g);
    out_mfma<<<(NTILE3 / 2 + 3) / 4 + 1, 256, 0, stream>>>(h16g, Wo, bo, out);
}